// Round 1
// 409.319 us; speedup vs baseline: 1.0926x; 1.0926x over previous
//
#include <hip/hip_runtime.h>
#include <hip/hip_bf16.h>

#define M_ROWS 16384
#define N_CODES 8192
#define DDIM    512
#define NCHUNK  512          // 16-code chunks per row (was 32-code / 256)
#define MARGIN  4.0f         // coarse-vs-exact distance margin (validated R5;
                             // semantics independent of chunk granularity)

typedef unsigned int u32;
typedef unsigned long long u64;
typedef unsigned short u16;
typedef __attribute__((ext_vector_type(8))) short short8;   // 8 bf16 = 4 VGPRs
typedef __attribute__((ext_vector_type(4))) float f32x4;

__device__ __forceinline__ u32 float_to_ordered(float f) {
    u32 u = __float_as_uint(f);
    return (u & 0x80000000u) ? ~u : (u | 0x80000000u);
}

__device__ __forceinline__ u16 bf16_rne(float x) {
    u32 u = __float_as_uint(x);
    u32 r = u + 0x7FFFu + ((u >> 16) & 1u);
    return (u16)(r >> 16);
}

__device__ __forceinline__ void gl_lds16(const void* g, void* l) {
    __builtin_amdgcn_global_load_lds((const __attribute__((address_space(1))) u32*)g,
                                     (__attribute__((address_space(3))) u32*)l,
                                     16, 0, 0);
}

__device__ __forceinline__ u64 umin64(u64 a, u64 b) { return a < b ? a : b; }

// ---------------------------------------------------------------------------
// Kernel 1: prep. Blocks [0,16384): z -> z_hi bf16.
// Blocks [16384,18432): emb -> e_hi bf16 + ||e||^2 (one wave per code).
// ---------------------------------------------------------------------------
__global__ __launch_bounds__(256) void vq_prep(
    const float4* __restrict__ z4, ushort4* __restrict__ zh,
    const float* __restrict__ emb, ushort4* __restrict__ eh,
    float* __restrict__ e_norms) {
    int b = blockIdx.x;
    if (b < (M_ROWS * DDIM) / 1024) {
        int i = b * 256 + threadIdx.x;
        float4 v = z4[i];
        ushort4 h;
        h.x = bf16_rne(v.x); h.y = bf16_rne(v.y);
        h.z = bf16_rne(v.z); h.w = bf16_rne(v.w);
        zh[i] = h;
    } else {
        int wave = threadIdx.x >> 6;
        int lane = threadIdx.x & 63;
        int code = (b - (M_ROWS * DDIM) / 1024) * 4 + wave;
        const float4* ep = (const float4*)(emb + (size_t)code * DDIM);
        size_t base4 = (size_t)code * (DDIM / 4);
        float s = 0.f;
        #pragma unroll
        for (int j = 0; j < 2; ++j) {
            int c = lane + 64 * j;
            float4 e = ep[c];
            s += e.x * e.x + e.y * e.y + e.z * e.z + e.w * e.w;
            ushort4 h;
            h.x = bf16_rne(e.x); h.y = bf16_rne(e.y);
            h.z = bf16_rne(e.z); h.w = bf16_rne(e.w);
            eh[base4 + c] = h;
        }
        #pragma unroll
        for (int off = 32; off; off >>= 1) s += __shfl_down(s, off, 64);
        if (lane == 0) e_norms[code] = s;
    }
}

// ---------------------------------------------------------------------------
// Kernel 2: phase-1 coarse GEMM (bf16 hi*hi) + per-(row, 16-col-chunk) minima.
// R2-verified structure: 128x128 tile, BK=32, 4 waves 2x2, 4x4 frags of
// 16x16x32. Epilogue now emits one minimum per j-tile (16 codes) as a single
// float4 store per owning lane.
// ---------------------------------------------------------------------------
__global__ __launch_bounds__(256) void vq_phase1(
    const u16* __restrict__ z_hi, const u16* __restrict__ e_hi,
    const float* __restrict__ e_norms,
    float* __restrict__ chunkmin) {
    __shared__ __align__(16) u16 ldsA[128][32];   // 8 KB
    __shared__ __align__(16) u16 ldsB[128][32];   // 8 KB

    const int tid  = threadIdx.x;
    const int wave = tid >> 6;
    const int lane = tid & 63;
    const int wm   = wave & 1;
    const int wn   = wave >> 1;
    const int row0 = blockIdx.x * 128;
    const int col0 = blockIdx.y * 128;

    const int srow = (wave << 5) + (lane >> 2);
    const int scol = (lane & 3) << 3;
    const u16* gA = z_hi + (size_t)(row0 + srow) * DDIM + scol;
    const u16* gB = e_hi + (size_t)(col0 + srow) * DDIM + scol;

    const int fm = (wm << 6) + (lane & 15);
    const int fn = (wn << 6) + (lane & 15);
    const int fk = (lane >> 4) << 3;

    f32x4 acc[4][4] = {};

    for (int it = 0; it < 16; ++it) {
        const int d0 = it << 5;
        __syncthreads();
        #pragma unroll
        for (int s = 0; s < 2; ++s) {
            const size_t go = (size_t)d0 + (size_t)s * 16 * DDIM;
            const int lr = (wave << 5) + (s << 4);
            gl_lds16(gA + go, &ldsA[lr][0]);
            gl_lds16(gB + go, &ldsB[lr][0]);
        }
        __syncthreads();

        short8 ah[4], bh[4];
        #pragma unroll
        for (int i = 0; i < 4; ++i) ah[i] = *(const short8*)&ldsA[fm + i * 16][fk];
        #pragma unroll
        for (int j = 0; j < 4; ++j) bh[j] = *(const short8*)&ldsB[fn + j * 16][fk];
        #pragma unroll
        for (int i = 0; i < 4; ++i)
            #pragma unroll
            for (int j = 0; j < 4; ++j)
                acc[i][j] = __builtin_amdgcn_mfma_f32_16x16x32_bf16(ah[i], bh[j], acc[i][j], 0, 0, 0);
    }

    // epilogue: C layout col = lane&15, row = (lane>>4)*4 + reg.
    // One chunk = one 16-col j-tile: min over the 16 cn lanes per j.
    const int cn = lane & 15;
    const int cg = lane >> 4;
    float en[4];
    #pragma unroll
    for (int j = 0; j < 4; ++j) en[j] = e_norms[col0 + (wn << 6) + j * 16 + cn];

    #pragma unroll
    for (int i = 0; i < 4; ++i)
        #pragma unroll
        for (int r = 0; r < 4; ++r) {
            float mv[4];
            #pragma unroll
            for (int j = 0; j < 4; ++j) {
                float d = en[j] - 2.0f * acc[i][j][r];
                d = fminf(d, __shfl_xor(d, 1, 64));
                d = fminf(d, __shfl_xor(d, 2, 64));
                d = fminf(d, __shfl_xor(d, 4, 64));
                d = fminf(d, __shfl_xor(d, 8, 64));
                mv[j] = d;
            }
            if (cn == 0) {
                int row_g = row0 + (wm << 6) + i * 16 + (cg << 2) + r;
                float4 o;
                o.x = mv[0]; o.y = mv[1]; o.z = mv[2]; o.w = mv[3];
                // chunk index = code/16 = blockIdx.y*8 + wn*4 + j
                *(float4*)&chunkmin[(size_t)row_g * NCHUNK + (blockIdx.y << 3) + (wn << 2)] = o;
            }
        }
}

// ---------------------------------------------------------------------------
// Kernel 3: fused finalize. One wave per row:
//  - min over 512 chunk-minima -> threshold
//  - ballot -> uniform candidate-chunk masks (no atomics, no queue)
//  - exact fp32 re-eval of candidate 16-code chunks (z row in registers)
//  - gather emb[winner] -> out_q, out_idx, per-block loss partial
// NOTE: chunkmin aliases out_q (2048 B/row each); this wave reads its row's
// chunkmin into registers before the out_q write at the end. Rows are
// wave-private, so the alias is race-free.
// ---------------------------------------------------------------------------
__global__ __launch_bounds__(256) void vq_finalize_rows(
    const float* __restrict__ z, const float* __restrict__ emb,
    const float* __restrict__ e_norms, const float* __restrict__ chunkmin,
    float* __restrict__ out_q, float* __restrict__ out_idx,
    float* __restrict__ partials) {
    const int wave = threadIdx.x >> 6;
    const int lane = threadIdx.x & 63;
    const int row  = blockIdx.x * 4 + wave;

    // ---- threshold from coarse chunk minima (512 per row) ----
    const float4* cm4 = (const float4*)(chunkmin + (size_t)row * NCHUNK);
    float4 v0 = cm4[lane];
    float4 v1 = cm4[64 + lane];
    float m = fminf(fminf(fminf(v0.x, v0.y), fminf(v0.z, v0.w)),
                    fminf(fminf(v1.x, v1.y), fminf(v1.z, v1.w)));
    #pragma unroll
    for (int off = 1; off < 64; off <<= 1) m = fminf(m, __shfl_xor(m, off, 64));
    const float thr = m + MARGIN;

    // ---- z row in registers: lane owns elements [lane*8, lane*8+8) ----
    const float4* z4 = (const float4*)(z + (size_t)row * DDIM);
    float4 za = z4[2 * lane];
    float4 zb = z4[2 * lane + 1];

    // ---- candidate masks (uniform across wave): 8 words ----
    u64 msk[8];
    msk[0] = __ballot(v0.x <= thr);
    msk[1] = __ballot(v0.y <= thr);
    msk[2] = __ballot(v0.z <= thr);
    msk[3] = __ballot(v0.w <= thr);
    msk[4] = __ballot(v1.x <= thr);
    msk[5] = __ballot(v1.y <= thr);
    msk[6] = __ballot(v1.z <= thr);
    msk[7] = __ballot(v1.w <= thr);

    u64 best = 0xFFFFFFFFFFFFFFFFull;
    #pragma unroll
    for (int p = 0; p < 2; ++p)
        #pragma unroll
        for (int j = 0; j < 4; ++j) {
            u64 mk = msk[p * 4 + j];
            while (mk) {
                int l = __ffsll((long long)mk) - 1;
                mk &= mk - 1;
                const int chunk = (p << 8) + (l << 2) + j;   // (p*64+l)*4 + j
                const int cbase = chunk << 4;                // 16 codes/chunk
                const float* eb = emb + (size_t)cbase * DDIM + lane * 8;
                float part[16];
                #pragma unroll
                for (int k = 0; k < 16; ++k) {
                    float4 ea = *(const float4*)(eb + (size_t)k * DDIM);
                    float4 e2 = *(const float4*)(eb + (size_t)k * DDIM + 4);
                    part[k] = za.x * ea.x + za.y * ea.y + za.z * ea.z + za.w * ea.w
                            + zb.x * e2.x + zb.y * e2.y + zb.z * e2.z + zb.w * e2.w;
                }
                #pragma unroll
                for (int off = 1; off < 64; off <<= 1)
                    #pragma unroll
                    for (int k = 0; k < 16; ++k)
                        part[k] += __shfl_xor(part[k], off, 64);
                #pragma unroll
                for (int k = 0; k < 16; ++k) {
                    float dist = e_norms[cbase + k] - 2.0f * part[k];
                    best = umin64(best, ((u64)float_to_ordered(dist) << 32) | (u32)(cbase + k));
                }
            }
        }

    // ---- gather winner, write outputs, loss partial ----
    const int idx = (int)(best & 0xFFFFFFFFull);
    const float* ew = emb + (size_t)idx * DDIM + lane * 8;
    float4 qa = *(const float4*)ew;
    float4 qb = *(const float4*)(ew + 4);
    float4* op = (float4*)(out_q + (size_t)row * DDIM);
    op[2 * lane]     = qa;
    op[2 * lane + 1] = qb;

    float dx, local = 0.f;
    dx = za.x - qa.x; local += dx * dx;  dx = za.y - qa.y; local += dx * dx;
    dx = za.z - qa.z; local += dx * dx;  dx = za.w - qa.w; local += dx * dx;
    dx = zb.x - qb.x; local += dx * dx;  dx = zb.y - qb.y; local += dx * dx;
    dx = zb.z - qb.z; local += dx * dx;  dx = zb.w - qb.w; local += dx * dx;
    #pragma unroll
    for (int off = 32; off; off >>= 1) local += __shfl_down(local, off, 64);

    __shared__ float wsum[4];
    if (lane == 0) { wsum[wave] = local; out_idx[row] = (float)idx; }
    __syncthreads();
    if (threadIdx.x == 0)
        partials[blockIdx.x] = wsum[0] + wsum[1] + wsum[2] + wsum[3];
}

// ---------------------------------------------------------------------------
// Kernel 4: reduce 4096 loss partials -> scalar loss.
// ---------------------------------------------------------------------------
__global__ __launch_bounds__(256) void vq_loss_reduce(
    const float* __restrict__ partials, float* __restrict__ out_loss) {
    __shared__ float red[256];
    float s = 0.f;
    for (int i = threadIdx.x; i < M_ROWS / 4; i += 256) s += partials[i];
    red[threadIdx.x] = s;
    __syncthreads();
    for (int off = 128; off; off >>= 1) {
        if (threadIdx.x < off) red[threadIdx.x] += red[threadIdx.x + off];
        __syncthreads();
    }
    if (threadIdx.x == 0)
        out_loss[0] = 0.25f * red[0] / ((float)M_ROWS * (float)DDIM);
}

extern "C" void kernel_launch(void* const* d_in, const int* in_sizes, int n_in,
                              void* d_out, int out_size, void* d_ws, size_t ws_size,
                              hipStream_t stream) {
    (void)in_sizes; (void)n_in; (void)out_size; (void)ws_size;
    const float* z   = (const float*)d_in[0];   // [16384, 512]
    const float* emb = (const float*)d_in[1];   // [8192, 512]

    float* out      = (float*)d_out;
    float* out_q    = out;
    float* out_idx  = out + (size_t)M_ROWS * DDIM;
    float* out_loss = out + (size_t)M_ROWS * DDIM + M_ROWS;

    // ws layout (requires ws_size >= 49152 + 24 MB):
    //   [0,32K)      e_norms
    //   [32K,48K)    loss partials
    //   [48K,+16MB)  z_hi bf16
    //   [.., +8MB)   e_hi bf16
    char* ws = (char*)d_ws;
    float* e_norms  = (float*)ws;
    float* partials = (float*)(ws + 32768);
    u16* z_hi = (u16*)(ws + 49152);
    u16* e_hi = (u16*)(ws + 49152 + (size_t)M_ROWS * DDIM * 2);

    // chunkmin [16384][512] f32 = 32 MB aliases out_q EXACTLY (2048 B/row
    // each). phase1 fills it; finalize reads its own row into registers
    // before overwriting that row's out_q. Rows are wave-private and the
    // kernels are stream-ordered -> race-free.
    float* chunkmin = out_q;

    const int zblocks = (M_ROWS * DDIM) / 1024;      // 16384
    const int eblocks = N_CODES / 4;                 // 2048
    vq_prep<<<zblocks + eblocks, 256, 0, stream>>>(
        (const float4*)z, (ushort4*)z_hi, emb, (ushort4*)e_hi, e_norms);

    vq_phase1<<<dim3(M_ROWS / 128, N_CODES / 128), 256, 0, stream>>>(
        z_hi, e_hi, e_norms, chunkmin);

    vq_finalize_rows<<<M_ROWS / 4, 256, 0, stream>>>(
        z, emb, e_norms, chunkmin, out_q, out_idx, partials);

    vq_loss_reduce<<<1, 256, 0, stream>>>(partials, out_loss);
}

// Round 2
// 367.889 us; speedup vs baseline: 1.2156x; 1.1126x over previous
//
#include <hip/hip_runtime.h>
#include <hip/hip_bf16.h>

#define M_ROWS 16384
#define N_CODES 8192
#define DDIM    512
#define NCHUNK  512          // 16-code chunks per row
#define MARGIN  4.0f         // coarse-vs-exact distance margin (validated R5)

typedef unsigned int u32;
typedef unsigned long long u64;
typedef unsigned short u16;
typedef __attribute__((ext_vector_type(8))) short short8;   // 8 bf16 = 4 VGPRs
typedef __attribute__((ext_vector_type(4))) float f32x4;

__device__ __forceinline__ u32 float_to_ordered(float f) {
    u32 u = __float_as_uint(f);
    return (u & 0x80000000u) ? ~u : (u | 0x80000000u);
}

__device__ __forceinline__ u16 bf16_rne(float x) {
    u32 u = __float_as_uint(x);
    u32 r = u + 0x7FFFu + ((u >> 16) & 1u);
    return (u16)(r >> 16);
}

__device__ __forceinline__ void gl_lds16(const void* g, void* l) {
    __builtin_amdgcn_global_load_lds((const __attribute__((address_space(1))) u32*)g,
                                     (__attribute__((address_space(3))) u32*)l,
                                     16, 0, 0);
}

__device__ __forceinline__ u64 umin64(u64 a, u64 b) { return a < b ? a : b; }

// DPP lane-permute within quads (VALU pipe, avoids ds_bpermute).
// 0xB1 = quad_perm [1,0,3,2] = xor 1;  0x4E = quad_perm [2,3,0,1] = xor 2.
#if __has_builtin(__builtin_amdgcn_update_dpp)
template <int CTRL>
__device__ __forceinline__ float dpp_mov(float x) {
    return __int_as_float(__builtin_amdgcn_update_dpp(
        __float_as_int(x), __float_as_int(x), CTRL, 0xF, 0xF, true));
}
#else
template <int CTRL>
__device__ __forceinline__ float dpp_mov(float x) {
    return __shfl_xor(x, CTRL == 0xB1 ? 1 : 2, 64);
}
#endif

// ---------------------------------------------------------------------------
// Kernel 1: prep. Blocks [0,16384): z -> z_hi bf16.
// Blocks [16384,18432): emb -> e_hi bf16 + ||e||^2 (one wave per code).
// ---------------------------------------------------------------------------
__global__ __launch_bounds__(256) void vq_prep(
    const float4* __restrict__ z4, ushort4* __restrict__ zh,
    const float* __restrict__ emb, ushort4* __restrict__ eh,
    float* __restrict__ e_norms) {
    int b = blockIdx.x;
    if (b < (M_ROWS * DDIM) / 1024) {
        int i = b * 256 + threadIdx.x;
        float4 v = z4[i];
        ushort4 h;
        h.x = bf16_rne(v.x); h.y = bf16_rne(v.y);
        h.z = bf16_rne(v.z); h.w = bf16_rne(v.w);
        zh[i] = h;
    } else {
        int wave = threadIdx.x >> 6;
        int lane = threadIdx.x & 63;
        int code = (b - (M_ROWS * DDIM) / 1024) * 4 + wave;
        const float4* ep = (const float4*)(emb + (size_t)code * DDIM);
        size_t base4 = (size_t)code * (DDIM / 4);
        float s = 0.f;
        #pragma unroll
        for (int j = 0; j < 2; ++j) {
            int c = lane + 64 * j;
            float4 e = ep[c];
            s += e.x * e.x + e.y * e.y + e.z * e.z + e.w * e.w;
            ushort4 h;
            h.x = bf16_rne(e.x); h.y = bf16_rne(e.y);
            h.z = bf16_rne(e.z); h.w = bf16_rne(e.w);
            eh[base4 + c] = h;
        }
        #pragma unroll
        for (int off = 32; off; off >>= 1) s += __shfl_down(s, off, 64);
        if (lane == 0) e_norms[code] = s;
    }
}

// ---------------------------------------------------------------------------
// Kernel 2: phase-1 coarse GEMM (bf16 hi*hi) + per-(row, 16-col-chunk) minima.
// 128x128 tile, BK=32, 4 waves 2x2, 4x4 frags of 16x16x32.
// Epilogue: reduce-scatter min over the 16 cn lanes — per (i,r):
//   ownership-split on lane bits 3 (xor8) and 2 (xor4), then quad-perm DPP
//   broadcast-min (xor1, xor2). 5 cross-lane stages instead of 16.
// ---------------------------------------------------------------------------
__global__ __launch_bounds__(256) void vq_phase1(
    const u16* __restrict__ z_hi, const u16* __restrict__ e_hi,
    const float* __restrict__ e_norms,
    float* __restrict__ chunkmin) {
    __shared__ __align__(16) u16 ldsA[128][32];   // 8 KB
    __shared__ __align__(16) u16 ldsB[128][32];   // 8 KB

    const int tid  = threadIdx.x;
    const int wave = tid >> 6;
    const int lane = tid & 63;
    const int wm   = wave & 1;
    const int wn   = wave >> 1;
    const int row0 = blockIdx.x * 128;
    const int col0 = blockIdx.y * 128;

    const int srow = (wave << 5) + (lane >> 2);
    const int scol = (lane & 3) << 3;
    const u16* gA = z_hi + (size_t)(row0 + srow) * DDIM + scol;
    const u16* gB = e_hi + (size_t)(col0 + srow) * DDIM + scol;

    const int fm = (wm << 6) + (lane & 15);
    const int fn = (wn << 6) + (lane & 15);
    const int fk = (lane >> 4) << 3;

    f32x4 acc[4][4] = {};

    for (int it = 0; it < 16; ++it) {
        const int d0 = it << 5;
        __syncthreads();
        #pragma unroll
        for (int s = 0; s < 2; ++s) {
            const size_t go = (size_t)d0 + (size_t)s * 16 * DDIM;
            const int lr = (wave << 5) + (s << 4);
            gl_lds16(gA + go, &ldsA[lr][0]);
            gl_lds16(gB + go, &ldsB[lr][0]);
        }
        __syncthreads();

        short8 ah[4], bh[4];
        #pragma unroll
        for (int i = 0; i < 4; ++i) ah[i] = *(const short8*)&ldsA[fm + i * 16][fk];
        #pragma unroll
        for (int j = 0; j < 4; ++j) bh[j] = *(const short8*)&ldsB[fn + j * 16][fk];
        #pragma unroll
        for (int i = 0; i < 4; ++i)
            #pragma unroll
            for (int j = 0; j < 4; ++j)
                acc[i][j] = __builtin_amdgcn_mfma_f32_16x16x32_bf16(ah[i], bh[j], acc[i][j], 0, 0, 0);
    }

    // epilogue: C layout col = lane&15, row = (lane>>4)*4 + reg.
    const int cn = lane & 15;
    const int cg = lane >> 4;
    float en[4];
    #pragma unroll
    for (int j = 0; j < 4; ++j) en[j] = e_norms[col0 + (wn << 6) + j * 16 + cn];

    #pragma unroll
    for (int i = 0; i < 4; ++i)
        #pragma unroll
        for (int r = 0; r < 4; ++r) {
            float mv[4];
            #pragma unroll
            for (int j = 0; j < 4; ++j) mv[j] = en[j] - 2.0f * acc[i][j][r];

            // stage xor8: regs 4->2; lane bit3 selects j-pair {0,1} vs {2,3}
            #pragma unroll
            for (int k = 0; k < 2; ++k) {
                float lo = mv[k], hi = mv[k + 2];
                float mine = (lane & 8) ? hi : lo;
                float thrs = (lane & 8) ? lo : hi;
                mv[k] = fminf(mine, __shfl_xor(thrs, 8, 64));
            }
            // stage xor4: regs 2->1; lane bit2 selects within pair
            {
                float lo = mv[0], hi = mv[1];
                float mine = (lane & 4) ? hi : lo;
                float thrs = (lane & 4) ? lo : hi;
                mv[0] = fminf(mine, __shfl_xor(thrs, 4, 64));
            }
            // broadcast-min over lane bits 0,1 via DPP quad_perm
            mv[0] = fminf(mv[0], dpp_mov<0xB1>(mv[0]));
            mv[0] = fminf(mv[0], dpp_mov<0x4E>(mv[0]));

            if ((cn & 3) == 0) {
                // j owned by this lane: j = 2*bit3 + bit2
                const int jj = ((cn >> 3) << 1) | ((cn >> 2) & 1);
                const int row_g = row0 + (wm << 6) + i * 16 + (cg << 2) + r;
                chunkmin[(size_t)row_g * NCHUNK + (blockIdx.y << 3) + (wn << 2) + jj] = mv[0];
            }
        }
}

// ---------------------------------------------------------------------------
// Kernel 3: fused finalize. One wave per row:
//  - min over 512 chunk-minima -> threshold
//  - ballot -> uniform candidate-chunk masks
//  - exact fp32 re-eval of candidate 16-code chunks via reduce-scatter
//    butterfly (12 DPP + 5 ds shuffles/chunk instead of 96), lane ends
//    owning code c = bitrev4(lane&15); single deferred 64-lane argmin.
// chunkmin aliases out_q (2048 B/row each); row data is read to registers
// before out_q is overwritten. Rows are wave-private -> race-free.
// ---------------------------------------------------------------------------
__global__ __launch_bounds__(256) void vq_finalize_rows(
    const float* __restrict__ z, const float* __restrict__ emb,
    const float* __restrict__ e_norms, const float* __restrict__ chunkmin,
    float* __restrict__ out_q, float* __restrict__ out_idx,
    float* __restrict__ partials) {
    const int wave = threadIdx.x >> 6;
    const int lane = threadIdx.x & 63;
    const int row  = blockIdx.x * 4 + wave;

    // ---- threshold from coarse chunk minima (512 per row) ----
    const float4* cm4 = (const float4*)(chunkmin + (size_t)row * NCHUNK);
    float4 v0 = cm4[lane];
    float4 v1 = cm4[64 + lane];
    float m = fminf(fminf(fminf(v0.x, v0.y), fminf(v0.z, v0.w)),
                    fminf(fminf(v1.x, v1.y), fminf(v1.z, v1.w)));
    #pragma unroll
    for (int off = 1; off < 64; off <<= 1) m = fminf(m, __shfl_xor(m, off, 64));
    const float thr = m + MARGIN;

    // ---- z row in registers: lane owns elements [lane*8, lane*8+8) ----
    const float4* z4 = (const float4*)(z + (size_t)row * DDIM);
    float4 za = z4[2 * lane];
    float4 zb = z4[2 * lane + 1];

    // ---- candidate masks (uniform across wave): 8 words ----
    u64 msk[8];
    msk[0] = __ballot(v0.x <= thr);
    msk[1] = __ballot(v0.y <= thr);
    msk[2] = __ballot(v0.z <= thr);
    msk[3] = __ballot(v0.w <= thr);
    msk[4] = __ballot(v1.x <= thr);
    msk[5] = __ballot(v1.y <= thr);
    msk[6] = __ballot(v1.z <= thr);
    msk[7] = __ballot(v1.w <= thr);

    // code owned by this lane after reduce-scatter: bit-reverse of lane&15
    const int cown = ((lane & 1) << 3) | ((lane & 2) << 1)
                   | ((lane & 4) >> 1) | ((lane & 8) >> 3);

    u64 best = 0xFFFFFFFFFFFFFFFFull;
    #pragma unroll
    for (int p = 0; p < 2; ++p)
        #pragma unroll
        for (int j = 0; j < 4; ++j) {
            u64 mk = msk[p * 4 + j];
            while (mk) {
                int l = __ffsll((long long)mk) - 1;
                mk &= mk - 1;
                const int chunk = (p << 8) + (l << 2) + j;   // (p*64+l)*4 + j
                const int cbase = chunk << 4;                // 16 codes/chunk
                const float* eb = emb + (size_t)cbase * DDIM + lane * 8;
                float part[16];
                #pragma unroll
                for (int k = 0; k < 16; ++k) {
                    float4 ea = *(const float4*)(eb + (size_t)k * DDIM);
                    float4 e2 = *(const float4*)(eb + (size_t)k * DDIM + 4);
                    part[k] = za.x * ea.x + za.y * ea.y + za.z * ea.z + za.w * ea.w
                            + zb.x * e2.x + zb.y * e2.y + zb.z * e2.z + zb.w * e2.w;
                }
                // reduce-scatter butterfly: identical summation tree to the
                // full xor-butterfly, so sums are bit-identical.
                #pragma unroll
                for (int k = 0; k < 8; ++k) {            // xor1 (DPP)
                    float lo = part[k], hi = part[k + 8];
                    float mine = (lane & 1) ? hi : lo;
                    float thrs = (lane & 1) ? lo : hi;
                    part[k] = mine + dpp_mov<0xB1>(thrs);
                }
                #pragma unroll
                for (int k = 0; k < 4; ++k) {            // xor2 (DPP)
                    float lo = part[k], hi = part[k + 4];
                    float mine = (lane & 2) ? hi : lo;
                    float thrs = (lane & 2) ? lo : hi;
                    part[k] = mine + dpp_mov<0x4E>(thrs);
                }
                #pragma unroll
                for (int k = 0; k < 2; ++k) {            // xor4
                    float lo = part[k], hi = part[k + 2];
                    float mine = (lane & 4) ? hi : lo;
                    float thrs = (lane & 4) ? lo : hi;
                    part[k] = mine + __shfl_xor(thrs, 4, 64);
                }
                {                                         // xor8
                    float lo = part[0], hi = part[1];
                    float mine = (lane & 8) ? hi : lo;
                    float thrs = (lane & 8) ? lo : hi;
                    part[0] = mine + __shfl_xor(thrs, 8, 64);
                }
                part[0] += __shfl_xor(part[0], 16, 64);   // replica sums
                part[0] += __shfl_xor(part[0], 32, 64);

                const int ci = cbase + cown;
                float dist = e_norms[ci] - 2.0f * part[0];
                best = umin64(best, ((u64)float_to_ordered(dist) << 32) | (u32)ci);
            }
        }

    // ---- single wave-wide argmin over per-lane bests ----
    #pragma unroll
    for (int off = 1; off < 64; off <<= 1)
        best = umin64(best, __shfl_xor(best, off, 64));

    // ---- gather winner, write outputs, loss partial ----
    const int idx = (int)(best & 0xFFFFFFFFull);
    const float* ew = emb + (size_t)idx * DDIM + lane * 8;
    float4 qa = *(const float4*)ew;
    float4 qb = *(const float4*)(ew + 4);
    float4* op = (float4*)(out_q + (size_t)row * DDIM);
    op[2 * lane]     = qa;
    op[2 * lane + 1] = qb;

    float dx, local = 0.f;
    dx = za.x - qa.x; local += dx * dx;  dx = za.y - qa.y; local += dx * dx;
    dx = za.z - qa.z; local += dx * dx;  dx = za.w - qa.w; local += dx * dx;
    dx = zb.x - qb.x; local += dx * dx;  dx = zb.y - qb.y; local += dx * dx;
    dx = zb.z - qb.z; local += dx * dx;  dx = zb.w - qb.w; local += dx * dx;
    #pragma unroll
    for (int off = 32; off; off >>= 1) local += __shfl_down(local, off, 64);

    __shared__ float wsum[4];
    if (lane == 0) { wsum[wave] = local; out_idx[row] = (float)idx; }
    __syncthreads();
    if (threadIdx.x == 0)
        partials[blockIdx.x] = wsum[0] + wsum[1] + wsum[2] + wsum[3];
}

// ---------------------------------------------------------------------------
// Kernel 4: reduce 4096 loss partials -> scalar loss.
// ---------------------------------------------------------------------------
__global__ __launch_bounds__(256) void vq_loss_reduce(
    const float* __restrict__ partials, float* __restrict__ out_loss) {
    __shared__ float red[256];
    float s = 0.f;
    for (int i = threadIdx.x; i < M_ROWS / 4; i += 256) s += partials[i];
    red[threadIdx.x] = s;
    __syncthreads();
    for (int off = 128; off; off >>= 1) {
        if (threadIdx.x < off) red[threadIdx.x] += red[threadIdx.x + off];
        __syncthreads();
    }
    if (threadIdx.x == 0)
        out_loss[0] = 0.25f * red[0] / ((float)M_ROWS * (float)DDIM);
}

extern "C" void kernel_launch(void* const* d_in, const int* in_sizes, int n_in,
                              void* d_out, int out_size, void* d_ws, size_t ws_size,
                              hipStream_t stream) {
    (void)in_sizes; (void)n_in; (void)out_size; (void)ws_size;
    const float* z   = (const float*)d_in[0];   // [16384, 512]
    const float* emb = (const float*)d_in[1];   // [8192, 512]

    float* out      = (float*)d_out;
    float* out_q    = out;
    float* out_idx  = out + (size_t)M_ROWS * DDIM;
    float* out_loss = out + (size_t)M_ROWS * DDIM + M_ROWS;

    // ws layout (requires ws_size >= 49152 + 24 MB):
    //   [0,32K) e_norms | [32K,48K) partials | [48K,+16MB) z_hi | +8MB e_hi
    char* ws = (char*)d_ws;
    float* e_norms  = (float*)ws;
    float* partials = (float*)(ws + 32768);
    u16* z_hi = (u16*)(ws + 49152);
    u16* e_hi = (u16*)(ws + 49152 + (size_t)M_ROWS * DDIM * 2);

    // chunkmin [16384][512] f32 = 32 MB aliases out_q EXACTLY (2048 B/row
    // each). phase1 fills it; finalize reads its own row into registers
    // before overwriting that row's out_q. Stream-ordered, wave-private rows.
    float* chunkmin = out_q;

    const int zblocks = (M_ROWS * DDIM) / 1024;      // 16384
    const int eblocks = N_CODES / 4;                 // 2048
    vq_prep<<<zblocks + eblocks, 256, 0, stream>>>(
        (const float4*)z, (ushort4*)z_hi, emb, (ushort4*)e_hi, e_norms);

    vq_phase1<<<dim3(M_ROWS / 128, N_CODES / 128), 256, 0, stream>>>(
        z_hi, e_hi, e_norms, chunkmin);

    vq_finalize_rows<<<M_ROWS / 4, 256, 0, stream>>>(
        z, emb, e_norms, chunkmin, out_q, out_idx, partials);

    vq_loss_reduce<<<1, 256, 0, stream>>>(partials, out_loss);
}

// Round 4
// 356.768 us; speedup vs baseline: 1.2535x; 1.0312x over previous
//
#include <hip/hip_runtime.h>
#include <hip/hip_bf16.h>

#define M_ROWS 16384
#define N_CODES 8192
#define DDIM    512
#define NCHUNK  512          // 16-code chunks per row
#define MARGIN  4.0f         // coarse-vs-exact distance margin (validated R5)

typedef unsigned int u32;
typedef unsigned long long u64;
typedef unsigned short u16;
typedef __attribute__((ext_vector_type(8))) short short8;   // 8 bf16 = 4 VGPRs
typedef __attribute__((ext_vector_type(4))) float f32x4;

__device__ __forceinline__ u32 float_to_ordered(float f) {
    u32 u = __float_as_uint(f);
    return (u & 0x80000000u) ? ~u : (u | 0x80000000u);
}

__device__ __forceinline__ u16 bf16_rne(float x) {
    u32 u = __float_as_uint(x);
    u32 r = u + 0x7FFFu + ((u >> 16) & 1u);
    return (u16)(r >> 16);
}

__device__ __forceinline__ void gl_lds16(const void* g, void* l) {
    __builtin_amdgcn_global_load_lds((const __attribute__((address_space(1))) u32*)g,
                                     (__attribute__((address_space(3))) u32*)l,
                                     16, 0, 0);
}

__device__ __forceinline__ u64 umin64(u64 a, u64 b) { return a < b ? a : b; }

// DPP lane-permute within quads (VALU pipe, avoids ds_bpermute).
// 0xB1 = quad_perm [1,0,3,2] = xor 1;  0x4E = quad_perm [2,3,0,1] = xor 2.
#if __has_builtin(__builtin_amdgcn_update_dpp)
template <int CTRL>
__device__ __forceinline__ float dpp_mov(float x) {
    return __int_as_float(__builtin_amdgcn_update_dpp(
        __float_as_int(x), __float_as_int(x), CTRL, 0xF, 0xF, true));
}
#else
template <int CTRL>
__device__ __forceinline__ float dpp_mov(float x) {
    return __shfl_xor(x, CTRL == 0xB1 ? 1 : 2, 64);
}
#endif

// ---------------------------------------------------------------------------
// Kernel 1: prep (unchanged).
// ---------------------------------------------------------------------------
__global__ __launch_bounds__(256) void vq_prep(
    const float4* __restrict__ z4, ushort4* __restrict__ zh,
    const float* __restrict__ emb, ushort4* __restrict__ eh,
    float* __restrict__ e_norms) {
    int b = blockIdx.x;
    if (b < (M_ROWS * DDIM) / 1024) {
        int i = b * 256 + threadIdx.x;
        float4 v = z4[i];
        ushort4 h;
        h.x = bf16_rne(v.x); h.y = bf16_rne(v.y);
        h.z = bf16_rne(v.z); h.w = bf16_rne(v.w);
        zh[i] = h;
    } else {
        int wave = threadIdx.x >> 6;
        int lane = threadIdx.x & 63;
        int code = (b - (M_ROWS * DDIM) / 1024) * 4 + wave;
        const float4* ep = (const float4*)(emb + (size_t)code * DDIM);
        size_t base4 = (size_t)code * (DDIM / 4);
        float s = 0.f;
        #pragma unroll
        for (int j = 0; j < 2; ++j) {
            int c = lane + 64 * j;
            float4 e = ep[c];
            s += e.x * e.x + e.y * e.y + e.z * e.z + e.w * e.w;
            ushort4 h;
            h.x = bf16_rne(e.x); h.y = bf16_rne(e.y);
            h.z = bf16_rne(e.z); h.w = bf16_rne(e.w);
            eh[base4 + c] = h;
        }
        #pragma unroll
        for (int off = 32; off; off >>= 1) s += __shfl_down(s, off, 64);
        if (lane == 0) e_norms[code] = s;
    }
}

// ---------------------------------------------------------------------------
// Kernel 2: phase-1 coarse GEMM, 256x256 8-phase schedule (T2+T3+T4+T5).
// 8 waves (2M x 4N), wave tile 128x64, BK=64, LDS 128 KiB double-buffered.
// Staging: global_load_lds with PRE-SWIZZLED global source (linear LDS dest);
// swizzle byte^=((row&7)<<4) applied identically on ds_read -> bank-uniform.
// Counted vmcnt(8) at phase boundaries 4 and 8 only; peeled drain iter.
// MFMA per-accumulator k-order identical to R2 -> chunkmin bit-identical.
// Sync protocol (audited R3->R4): per-wave vmcnt(N) + following s_barrier
// gives the cross-wave LDS-visibility guarantee; every stage into a buffer
// is issued after the barrier that follows the last consumer's lgkmcnt(0).
// ---------------------------------------------------------------------------

// stage one 32KB tile (256 rows x 64 k bf16) into linear LDS; 4 x 8KB issues.
// Source address pre-swizzled so that a swizzled ds_read returns logical data.
__device__ __forceinline__ void stage_tile(const char* gbase, int kt,
                                           void* lds, int tid) {
    #pragma unroll
    for (int s = 0; s < 4; ++s) {
        const int row_l = (s << 6) + (tid >> 3);
        const int cb = (((tid & 7) ^ (row_l & 7)) << 4);
        const char* g = gbase + (size_t)row_l * (DDIM * 2) + ((size_t)kt << 7) + cb;
        char* l = (char*)lds + (s << 13) + (tid << 4);
        gl_lds16(g, l);
    }
}

#define BAR() __builtin_amdgcn_s_barrier()
#define LGK0() do { asm volatile("s_waitcnt lgkmcnt(0)" ::: "memory"); \
                    __builtin_amdgcn_sched_barrier(0); } while (0)
#define VMC8() do { asm volatile("s_waitcnt vmcnt(8)" ::: "memory"); } while (0)
#define VMC0() do { asm volatile("s_waitcnt vmcnt(0)" ::: "memory"); } while (0)

#define LDA(BUF, MH) do {                                                      \
    _Pragma("unroll") for (int i_ = 0; i_ < 4; ++i_) {                         \
        _Pragma("unroll") for (int kk_ = 0; kk_ < 2; ++kk_) {                  \
            const int row_ = (wm << 7) + ((((MH) << 2) + i_) << 4) + fr;       \
            const int cb_ = (kk_ << 6) + fkb;                                  \
            a[i_][kk_] = *(const short8*)((const char*)&ldsA[BUF][0][0]        \
                + row_ * 128 + (cb_ ^ ((row_ & 7) << 4)));                     \
        } } } while (0)

#define LDB(BUF, NH) do {                                                      \
    _Pragma("unroll") for (int j_ = 0; j_ < 2; ++j_) {                         \
        _Pragma("unroll") for (int kk_ = 0; kk_ < 2; ++kk_) {                  \
            const int row_ = (wn << 6) + ((((NH) << 1) + j_) << 4) + fr;       \
            const int cb_ = (kk_ << 6) + fkb;                                  \
            b[(NH) * 2 + j_][kk_] = *(const short8*)((const char*)&ldsB[BUF][0][0] \
                + row_ * 128 + (cb_ ^ ((row_ & 7) << 4)));                     \
        } } } while (0)

#define MFMA_Q(MH, NH) do {                                                    \
    __builtin_amdgcn_s_setprio(1);                                             \
    _Pragma("unroll") for (int i_ = 0; i_ < 4; ++i_) {                         \
        _Pragma("unroll") for (int j_ = 0; j_ < 2; ++j_) {                     \
            _Pragma("unroll") for (int kk_ = 0; kk_ < 2; ++kk_) {              \
                acc[(MH) * 4 + i_][(NH) * 2 + j_] =                            \
                    __builtin_amdgcn_mfma_f32_16x16x32_bf16(                   \
                        a[i_][kk_], b[(NH) * 2 + j_][kk_],                     \
                        acc[(MH) * 4 + i_][(NH) * 2 + j_], 0, 0, 0);           \
        } } }                                                                  \
    __builtin_amdgcn_s_setprio(0);                                             \
} while (0)

// One iteration = 2 K-tiles (buf0 then buf1), 8 phases, 2 barriers each.
// Stage-safety: B(buf) fully read by end of ph2/ph6, A(buf) by end of
// ph3/ph7 (each wave's lgkmcnt(0) precedes the phase-ending barrier).
#define PH_ITER(SE, VMA, VMB, NK0, NK1)                                        \
    LDA(0, 0); LDB(0, 0);                                                      \
    BAR(); LGK0(); MFMA_Q(0, 0); BAR();                                        \
    LDB(0, 1);                                                                 \
    BAR(); LGK0(); MFMA_Q(0, 1); BAR();                                        \
    LDA(0, 1);                                                                 \
    if (SE) stage_tile(gB0, (NK0), &ldsB[0][0][0], tid);                       \
    BAR(); LGK0(); MFMA_Q(1, 0); BAR();                                        \
    if (SE) stage_tile(gA0, (NK0), &ldsA[0][0][0], tid);                       \
    BAR(); MFMA_Q(1, 1); VMA; BAR();                                           \
    LDA(1, 0); LDB(1, 0);                                                      \
    BAR(); LGK0(); MFMA_Q(0, 0); BAR();                                        \
    LDB(1, 1);                                                                 \
    BAR(); LGK0(); MFMA_Q(0, 1); BAR();                                        \
    LDA(1, 1);                                                                 \
    if (SE) stage_tile(gB0, (NK1), &ldsB[1][0][0], tid);                       \
    BAR(); LGK0(); MFMA_Q(1, 0); BAR();                                        \
    if (SE) stage_tile(gA0, (NK1), &ldsA[1][0][0], tid);                       \
    BAR(); MFMA_Q(1, 1); VMB; BAR();

__global__ __launch_bounds__(512, 2) void vq_phase1(
    const u16* __restrict__ z_hi, const u16* __restrict__ e_hi,
    const float* __restrict__ e_norms,
    float* __restrict__ chunkmin) {
    __shared__ __align__(16) u16 ldsA[2][256][64];   // 64 KB
    __shared__ __align__(16) u16 ldsB[2][256][64];   // 64 KB

    const int tid  = threadIdx.x;
    const int lane = tid & 63;
    const int wid  = tid >> 6;
    const int wm   = wid >> 2;          // 0..1
    const int wn   = wid & 3;           // 0..3
    const int row0 = blockIdx.x << 8;
    const int col0 = blockIdx.y << 8;
    const int fr   = lane & 15;
    const int fkb  = (lane >> 4) << 4;  // k byte offset within 32-elem slice

    const char* gA0 = (const char*)z_hi + (size_t)row0 * (DDIM * 2);
    const char* gB0 = (const char*)e_hi + (size_t)col0 * (DDIM * 2);

    f32x4 acc[8][4] = {};
    short8 a[4][2], b[4][2];

    // prologue: stage K-tiles 0 (buf0) and 1 (buf1)
    stage_tile(gA0, 0, &ldsA[0][0][0], tid);
    stage_tile(gB0, 0, &ldsB[0][0][0], tid);
    stage_tile(gA0, 1, &ldsA[1][0][0], tid);
    stage_tile(gB0, 1, &ldsB[1][0][0], tid);
    VMC8(); BAR();

    #pragma unroll 1
    for (int t = 0; t < 3; ++t) {
        const int nk0 = 2 * t + 2, nk1 = 2 * t + 3;
        PH_ITER(1, VMC8(), VMC8(), nk0, nk1)
    }
    // drain iteration: no stages; vmcnt(0) before buf1 phases.
    PH_ITER(0, VMC0(), ((void)0), 0, 0)

    // epilogue: C layout col = lane&15, row = (lane>>4)*4 + reg.
    // reduce-scatter min over the 16 cn lanes per (i, r) — same tree as R2.
    const int cn = lane & 15;
    const int cg = lane >> 4;
    float en[4];
    #pragma unroll
    for (int j = 0; j < 4; ++j) en[j] = e_norms[col0 + (wn << 6) + j * 16 + cn];

    #pragma unroll
    for (int i = 0; i < 8; ++i)
        #pragma unroll
        for (int r = 0; r < 4; ++r) {
            float mv[4];
            #pragma unroll
            for (int j = 0; j < 4; ++j) mv[j] = en[j] - 2.0f * acc[i][j][r];

            // stage xor8: regs 4->2; lane bit3 selects j-pair {0,1} vs {2,3}
            #pragma unroll
            for (int k = 0; k < 2; ++k) {
                float lo = mv[k], hi = mv[k + 2];
                float mine = (lane & 8) ? hi : lo;
                float thrs = (lane & 8) ? lo : hi;
                mv[k] = fminf(mine, __shfl_xor(thrs, 8, 64));
            }
            // stage xor4: regs 2->1; lane bit2 selects within pair
            {
                float lo = mv[0], hi = mv[1];
                float mine = (lane & 4) ? hi : lo;
                float thrs = (lane & 4) ? lo : hi;
                mv[0] = fminf(mine, __shfl_xor(thrs, 4, 64));
            }
            // broadcast-min over lane bits 0,1 via DPP quad_perm
            mv[0] = fminf(mv[0], dpp_mov<0xB1>(mv[0]));
            mv[0] = fminf(mv[0], dpp_mov<0x4E>(mv[0]));

            if ((cn & 3) == 0) {
                const int jj = ((cn >> 3) << 1) | ((cn >> 2) & 1);
                const int row_g = row0 + (wm << 7) + (i << 4) + (cg << 2) + r;
                chunkmin[(size_t)row_g * NCHUNK + (col0 >> 4) + (wn << 2) + jj] = mv[0];
            }
        }
}

// ---------------------------------------------------------------------------
// Kernel 3: fused finalize (unchanged from R2).
// ---------------------------------------------------------------------------
__global__ __launch_bounds__(256) void vq_finalize_rows(
    const float* __restrict__ z, const float* __restrict__ emb,
    const float* __restrict__ e_norms, const float* __restrict__ chunkmin,
    float* __restrict__ out_q, float* __restrict__ out_idx,
    float* __restrict__ partials) {
    const int wave = threadIdx.x >> 6;
    const int lane = threadIdx.x & 63;
    const int row  = blockIdx.x * 4 + wave;

    const float4* cm4 = (const float4*)(chunkmin + (size_t)row * NCHUNK);
    float4 v0 = cm4[lane];
    float4 v1 = cm4[64 + lane];
    float m = fminf(fminf(fminf(v0.x, v0.y), fminf(v0.z, v0.w)),
                    fminf(fminf(v1.x, v1.y), fminf(v1.z, v1.w)));
    #pragma unroll
    for (int off = 1; off < 64; off <<= 1) m = fminf(m, __shfl_xor(m, off, 64));
    const float thr = m + MARGIN;

    const float4* z4 = (const float4*)(z + (size_t)row * DDIM);
    float4 za = z4[2 * lane];
    float4 zb = z4[2 * lane + 1];

    u64 msk[8];
    msk[0] = __ballot(v0.x <= thr);
    msk[1] = __ballot(v0.y <= thr);
    msk[2] = __ballot(v0.z <= thr);
    msk[3] = __ballot(v0.w <= thr);
    msk[4] = __ballot(v1.x <= thr);
    msk[5] = __ballot(v1.y <= thr);
    msk[6] = __ballot(v1.z <= thr);
    msk[7] = __ballot(v1.w <= thr);

    const int cown = ((lane & 1) << 3) | ((lane & 2) << 1)
                   | ((lane & 4) >> 1) | ((lane & 8) >> 3);

    u64 best = 0xFFFFFFFFFFFFFFFFull;
    #pragma unroll
    for (int p = 0; p < 2; ++p)
        #pragma unroll
        for (int j = 0; j < 4; ++j) {
            u64 mk = msk[p * 4 + j];
            while (mk) {
                int l = __ffsll((long long)mk) - 1;
                mk &= mk - 1;
                const int chunk = (p << 8) + (l << 2) + j;
                const int cbase = chunk << 4;
                const float* eb = emb + (size_t)cbase * DDIM + lane * 8;
                float part[16];
                #pragma unroll
                for (int k = 0; k < 16; ++k) {
                    float4 ea = *(const float4*)(eb + (size_t)k * DDIM);
                    float4 e2 = *(const float4*)(eb + (size_t)k * DDIM + 4);
                    part[k] = za.x * ea.x + za.y * ea.y + za.z * ea.z + za.w * ea.w
                            + zb.x * e2.x + zb.y * e2.y + zb.z * e2.z + zb.w * e2.w;
                }
                #pragma unroll
                for (int k = 0; k < 8; ++k) {            // xor1 (DPP)
                    float lo = part[k], hi = part[k + 8];
                    float mine = (lane & 1) ? hi : lo;
                    float thrs = (lane & 1) ? lo : hi;
                    part[k] = mine + dpp_mov<0xB1>(thrs);
                }
                #pragma unroll
                for (int k = 0; k < 4; ++k) {            // xor2 (DPP)
                    float lo = part[k], hi = part[k + 4];
                    float mine = (lane & 2) ? hi : lo;
                    float thrs = (lane & 2) ? lo : hi;
                    part[k] = mine + dpp_mov<0x4E>(thrs);
                }
                #pragma unroll
                for (int k = 0; k < 2; ++k) {            // xor4
                    float lo = part[k], hi = part[k + 2];
                    float mine = (lane & 4) ? hi : lo;
                    float thrs = (lane & 4) ? lo : hi;
                    part[k] = mine + __shfl_xor(thrs, 4, 64);
                }
                {                                         // xor8
                    float lo = part[0], hi = part[1];
                    float mine = (lane & 8) ? hi : lo;
                    float thrs = (lane & 8) ? lo : hi;
                    part[0] = mine + __shfl_xor(thrs, 8, 64);
                }
                part[0] += __shfl_xor(part[0], 16, 64);
                part[0] += __shfl_xor(part[0], 32, 64);

                const int ci = cbase + cown;
                float dist = e_norms[ci] - 2.0f * part[0];
                best = umin64(best, ((u64)float_to_ordered(dist) << 32) | (u32)ci);
            }
        }

    #pragma unroll
    for (int off = 1; off < 64; off <<= 1)
        best = umin64(best, __shfl_xor(best, off, 64));

    const int idx = (int)(best & 0xFFFFFFFFull);
    const float* ew = emb + (size_t)idx * DDIM + lane * 8;
    float4 qa = *(const float4*)ew;
    float4 qb = *(const float4*)(ew + 4);
    float4* op = (float4*)(out_q + (size_t)row * DDIM);
    op[2 * lane]     = qa;
    op[2 * lane + 1] = qb;

    float dx, local = 0.f;
    dx = za.x - qa.x; local += dx * dx;  dx = za.y - qa.y; local += dx * dx;
    dx = za.z - qa.z; local += dx * dx;  dx = za.w - qa.w; local += dx * dx;
    dx = zb.x - qb.x; local += dx * dx;  dx = zb.y - qb.y; local += dx * dx;
    dx = zb.z - qb.z; local += dx * dx;  dx = zb.w - qb.w; local += dx * dx;
    #pragma unroll
    for (int off = 32; off; off >>= 1) local += __shfl_down(local, off, 64);

    __shared__ float wsum[4];
    if (lane == 0) { wsum[wave] = local; out_idx[row] = (float)idx; }
    __syncthreads();
    if (threadIdx.x == 0)
        partials[blockIdx.x] = wsum[0] + wsum[1] + wsum[2] + wsum[3];
}

// ---------------------------------------------------------------------------
// Kernel 4: reduce 4096 loss partials -> scalar loss.
// ---------------------------------------------------------------------------
__global__ __launch_bounds__(256) void vq_loss_reduce(
    const float* __restrict__ partials, float* __restrict__ out_loss) {
    __shared__ float red[256];
    float s = 0.f;
    for (int i = threadIdx.x; i < M_ROWS / 4; i += 256) s += partials[i];
    red[threadIdx.x] = s;
    __syncthreads();
    for (int off = 128; off; off >>= 1) {
        if (threadIdx.x < off) red[threadIdx.x] += red[threadIdx.x + off];
        __syncthreads();
    }
    if (threadIdx.x == 0)
        out_loss[0] = 0.25f * red[0] / ((float)M_ROWS * (float)DDIM);
}

extern "C" void kernel_launch(void* const* d_in, const int* in_sizes, int n_in,
                              void* d_out, int out_size, void* d_ws, size_t ws_size,
                              hipStream_t stream) {
    (void)in_sizes; (void)n_in; (void)out_size; (void)ws_size;
    const float* z   = (const float*)d_in[0];   // [16384, 512]
    const float* emb = (const float*)d_in[1];   // [8192, 512]

    float* out      = (float*)d_out;
    float* out_q    = out;
    float* out_idx  = out + (size_t)M_ROWS * DDIM;
    float* out_loss = out + (size_t)M_ROWS * DDIM + M_ROWS;

    // ws layout (requires ws_size >= 49152 + 24 MB):
    //   [0,32K) e_norms | [32K,48K) partials | [48K,+16MB) z_hi | +8MB e_hi
    char* ws = (char*)d_ws;
    float* e_norms  = (float*)ws;
    float* partials = (float*)(ws + 32768);
    u16* z_hi = (u16*)(ws + 49152);
    u16* e_hi = (u16*)(ws + 49152 + (size_t)M_ROWS * DDIM * 2);

    // chunkmin [16384][512] f32 = 32 MB aliases out_q EXACTLY (2048 B/row
    // each). phase1 fills it; finalize reads its own row into registers
    // before overwriting that row's out_q. Stream-ordered, wave-private rows.
    float* chunkmin = out_q;

    const int zblocks = (M_ROWS * DDIM) / 1024;      // 16384
    const int eblocks = N_CODES / 4;                 // 2048
    vq_prep<<<zblocks + eblocks, 256, 0, stream>>>(
        (const float4*)z, (ushort4*)z_hi, emb, (ushort4*)e_hi, e_norms);

    vq_phase1<<<dim3(M_ROWS / 256, N_CODES / 256), 512, 0, stream>>>(
        z_hi, e_hi, e_norms, chunkmin);

    vq_finalize_rows<<<M_ROWS / 4, 256, 0, stream>>>(
        z, emb, e_norms, chunkmin, out_q, out_idx, partials);

    vq_loss_reduce<<<1, 256, 0, stream>>>(partials, out_loss);
}